// Round 9
// baseline (1325.786 us; speedup 1.0000x reference)
//
#include <hip/hip_runtime.h>
#include <math.h>

#define LSEQ 512
#define BATCH 64
#define EDIM 256
#define HD 128            // H2
#define G4 512            // 4*H2
#define NTAG 9
#define MTOT (LSEQ*BATCH) // 32768

typedef _Float16 f16x8 __attribute__((ext_vector_type(8)));
typedef float    f32x4 __attribute__((ext_vector_type(4)));

__device__ __forceinline__ float fsig(float x){
    return __builtin_amdgcn_rcpf(1.0f + __expf(-x));
}
__device__ __forceinline__ float ftanh(float x){
    return 1.0f - 2.0f*__builtin_amdgcn_rcpf(1.0f + __expf(2.0f*x));
}
// LDS-only barrier: does NOT drain vmcnt, so global prefetches stay in flight.
__device__ __forceinline__ void wg_barrier_lds(){
    asm volatile("s_waitcnt lgkmcnt(0)" ::: "memory");
    __builtin_amdgcn_s_barrier();
    asm volatile("" ::: "memory");
}

// ---------------- GEMM (MFMA, f16 3-term split): gx[dir][l*64+b][j] = emb[sent[b][l]] . w_ih[j] + bias
#define GBM 128
#define GBN 128
__global__ __launch_bounds__(256) void gx_gemm(
    const int* __restrict__ sent, const float* __restrict__ emb,
    const float* __restrict__ wf, const float* __restrict__ wb,
    const float* __restrict__ bf, const float* __restrict__ bb,
    float* __restrict__ gx)
{
    __shared__ f16x8 Ah[512], Am[512], Bh[512], Bm[512];
    __shared__ int sidx[GBM];
    const int tid = threadIdx.x;
    const int bm0 = blockIdx.x * GBM;
    const int bn0 = blockIdx.y * GBN;
    if (tid < GBM){
        int m = bm0 + tid;
        sidx[tid] = sent[(m & 63)*LSEQ + (m >> 6)];
    }
    __syncthreads();

    const float* srcA[2];
    const float* srcB[2];
    #pragma unroll
    for (int p=0;p<2;p++){
        const int d   = tid + 256*p;
        const int row = (d>>6)*16 + (d&15);
        const int kq  = (d>>4)&3;
        srcA[p] = emb + (size_t)sidx[row]*EDIM + kq*8;
        const int col = bn0 + row;
        srcB[p] = ((col < G4) ? (wf + (size_t)col*EDIM)
                              : (wb + (size_t)(col-G4)*EDIM)) + kq*8;
    }

    const int lane = tid & 63;
    const int wid  = tid >> 6;
    const int wm   = wid >> 1;
    const int wn   = wid & 1;

    f32x4 acc[4][4];
    #pragma unroll
    for (int i=0;i<4;i++)
        #pragma unroll
        for (int jj=0;jj<4;jj++)
            #pragma unroll
            for (int e=0;e<4;e++) acc[i][jj][e]=0.f;

    float4 ra[2][2], rb[2][2];
    #define LOADC(K0)  { _Pragma("unroll") for (int p=0;p<2;p++){ \
        ra[p][0] = *(const float4*)(srcA[p] + (K0));  ra[p][1] = *(const float4*)(srcA[p] + (K0) + 4); \
        rb[p][0] = *(const float4*)(srcB[p] + (K0));  rb[p][1] = *(const float4*)(srcB[p] + (K0) + 4); } }

    LOADC(0);
    for (int c=0;c<8;c++){
        wg_barrier_lds();
        #pragma unroll
        for (int p=0;p<2;p++){
            float va[8] = {ra[p][0].x, ra[p][0].y, ra[p][0].z, ra[p][0].w,
                           ra[p][1].x, ra[p][1].y, ra[p][1].z, ra[p][1].w};
            float vb[8] = {rb[p][0].x, rb[p][0].y, rb[p][0].z, rb[p][0].w,
                           rb[p][1].x, rb[p][1].y, rb[p][1].z, rb[p][1].w};
            f16x8 ahh, amm, bhh, bmm;
            #pragma unroll
            for (int i=0;i<8;i++){
                _Float16 hv = (_Float16)va[i];
                ahh[i] = hv; amm[i] = (_Float16)(va[i] - (float)hv);
                _Float16 hw = (_Float16)vb[i];
                bhh[i] = hw; bmm[i] = (_Float16)(vb[i] - (float)hw);
            }
            Ah[tid + 256*p] = ahh;  Am[tid + 256*p] = amm;
            Bh[tid + 256*p] = bhh;  Bm[tid + 256*p] = bmm;
        }
        if (c < 7) LOADC(32*(c+1));
        wg_barrier_lds();

        f16x8 ah[4], am[4];
        #pragma unroll
        for (int mt=0;mt<4;mt++){
            ah[mt] = Ah[(wm*4+mt)*64 + lane];
            am[mt] = Am[(wm*4+mt)*64 + lane];
        }
        #pragma unroll
        for (int nt=0;nt<4;nt++){
            f16x8 bh = Bh[(wn*4+nt)*64 + lane];
            f16x8 bm = Bm[(wn*4+nt)*64 + lane];
            #pragma unroll
            for (int mt=0;mt<4;mt++){
                acc[mt][nt] = __builtin_amdgcn_mfma_f32_16x16x32_f16(ah[mt], bh, acc[mt][nt], 0,0,0);
                acc[mt][nt] = __builtin_amdgcn_mfma_f32_16x16x32_f16(am[mt], bh, acc[mt][nt], 0,0,0);
                acc[mt][nt] = __builtin_amdgcn_mfma_f32_16x16x32_f16(ah[mt], bm, acc[mt][nt], 0,0,0);
            }
        }
    }
    #undef LOADC

    #pragma unroll
    for (int mt=0;mt<4;mt++){
        #pragma unroll
        for (int nt=0;nt<4;nt++){
            const int n   = bn0 + wn*64 + nt*16 + (lane & 15);
            const int dir = n >> 9;
            const int j   = n & 511;
            const float bias = (n < G4) ? bf[n] : bb[n - G4];
            const int mrow = bm0 + wm*64 + mt*16 + ((lane >> 4) << 2);
            float* o = gx + (size_t)dir*((size_t)MTOT*G4) + (size_t)mrow*G4 + j;
            o[0*G4] = acc[mt][nt][0] + bias;
            o[1*G4] = acc[mt][nt][1] + bias;
            o[2*G4] = acc[mt][nt][2] + bias;
            o[3*G4] = acc[mt][nt][3] + bias;
        }
    }
}

// ---------------- Pack W_hh k-half-1 into stream-optimal layout:
// sbuf[dir][c][tt] (float4) = W[row][64 + 4*(c&15) .. +3], row = (c<16) ? tt : tt+256.
// Per-step stream reads become lane-contiguous (64 lanes x 16B = 1KB per instr).
__global__ __launch_bounds__(256) void pack_whh(
    const float* __restrict__ whf, const float* __restrict__ whb, float4* __restrict__ sbuf)
{
    const int dir = blockIdx.x;          // 0..1
    const int c   = blockIdx.y;          // 0..31
    const int tt  = threadIdx.x;         // 0..255
    const float* W = dir ? whb : whf;
    const int row = (c < 16) ? tt : (tt + 256);
    const int k0  = 64 + 4*(c & 15);
    sbuf[((size_t)dir*32 + c)*256 + tt] = *(const float4*)&W[(size_t)row*HD + k0];
}

// ---------------- LSTM recurrence v6: dual-pipe weight delivery.
// 128 WGs = (dir,b), 512 threads: thread = (kh = t>>8, gr = t&255) -> rows gr, gr+256.
// kh=0 (waves 0-3): weights k[0:64) from a 128KB XOR-swizzled LDS cache (LDS pipe).
// kh=1 (waves 4-7): weights k[64:128) streamed from packed sbuf (L2 port pipe).
// The two ~128KB/step transfers run on independent pipes and overlap.
// (R3-R8 lesson: VGPR residency is RA-capped at 64-88 regs for 512/1024-thr WGs —
//  unreachable; this design has NO dependence on register allocation behavior.)
#define DOT4(W,H) ((W).x*(H).x + (W).y*(H).y + (W).z*(H).z + (W).w*(H).w)
__global__ __launch_bounds__(512) void lstm_rec(
    const float* __restrict__ gx,
    const float* __restrict__ whf, const float* __restrict__ whb,
    const int* __restrict__ pm,
    const float4* __restrict__ sbuf,
    float* __restrict__ lout)
{
    const int wg  = blockIdx.x;      // 0..127
    const int dir = wg >> 6;
    const int b   = wg & 63;
    const int t   = threadIdx.x;     // 0..511
    const int kh  = t >> 8;          // 0: LDS-cached k-half, 1: streamed k-half
    const int gr  = t & 255;         // rows gr and gr+256
    const int j   = t & 127;         // unit index for update phase (t<128)

    __shared__ float4 wl4[256*32];   // 128KB swizzled weight cache (k in [0,64))
    __shared__ float  pact2[2][512];
    __shared__ float  hsh[HD];
    __shared__ int    pms[LSEQ];

    // one-time fills
    if (t < 256){
        const float* W = dir ? whb : whf;
        const int sw = t & 7;
        #pragma unroll
        for (int i=0;i<32;i++){
            const int row = (i < 16) ? t : (t + 256);
            wl4[t*32 + (i ^ sw)] = *(const float4*)&W[(size_t)row*HD + 4*(i & 15)];
        }
    }
    for (int q=t; q<LSEQ; q+=512) pms[q] = pm[b*LSEQ + q];
    if (t < HD) hsh[t] = 0.f;
    float c = 0.f, h = 0.f;

    const size_t stepel = (size_t)BATCH*G4;
    const float* gxb = gx + (size_t)dir*((size_t)MTOT*G4) + (size_t)b*G4
                          + (dir ? (size_t)(LSEQ-1)*stepel : 0);
    const ptrdiff_t dstep = dir ? -(ptrdiff_t)stepel : (ptrdiff_t)stepel;
    float* op = lout + (size_t)b*256 + dir*HD + j;   // used only when t<128

    // depth-2 gx prefetch queue (lgkm-only barriers keep vmcnt in flight)
    float4 gc = {0,0,0,0}, gn1 = {0,0,0,0};
    if (t < 128){
        gc.x  = gxb[j];          gc.y  = gxb[j+128];
        gc.z  = gxb[j+256];      gc.w  = gxb[j+384];
        const float* p1 = gxb + dstep;
        gn1.x = p1[j];           gn1.y = p1[j+128];
        gn1.z = p1[j+256];       gn1.w = p1[j+384];
    }
    wg_barrier_lds();   // wl4 + hsh + pms visible

    const float4* wb4 = &wl4[gr*32];                     // kh==0 path
    const int sw = gr & 7;
    const float4* sb  = sbuf + (size_t)dir*8192 + gr;    // kh==1 path (stride 256 float4/chunk)

    for (int s=0; s<LSEQ; s++){
        float4 gn2 = {0,0,0,0};
        if (t < 128 && s+2 < LSEQ){
            const float* p = gxb + (ptrdiff_t)(s+2)*dstep;
            gn2.x = p[j]; gn2.y = p[j+128]; gn2.z = p[j+256]; gn2.w = p[j+384];
        }
        const int l = dir ? (LSEQ-1-s) : s;
        const int pmv = pms[l];

        float a = 0.f, bb = 0.f;
        if (kh == 0){
            #pragma unroll
            for (int g=0; g<4; g++){
                float4 h0 = *(const float4*)&hsh[g*16 +  0];
                float4 h1 = *(const float4*)&hsh[g*16 +  4];
                float4 h2 = *(const float4*)&hsh[g*16 +  8];
                float4 h3 = *(const float4*)&hsh[g*16 + 12];
                float4 wA0 = wb4[(g*4+0) ^ sw], wA1 = wb4[(g*4+1) ^ sw],
                       wA2 = wb4[(g*4+2) ^ sw], wA3 = wb4[(g*4+3) ^ sw];
                float4 wB0 = wb4[16 + ((g*4+0) ^ sw)], wB1 = wb4[16 + ((g*4+1) ^ sw)],
                       wB2 = wb4[16 + ((g*4+2) ^ sw)], wB3 = wb4[16 + ((g*4+3) ^ sw)];
                a  += (DOT4(wA0,h0)+DOT4(wA1,h1)) + (DOT4(wA2,h2)+DOT4(wA3,h3));
                bb += (DOT4(wB0,h0)+DOT4(wB1,h1)) + (DOT4(wB2,h2)+DOT4(wB3,h3));
            }
        } else {
            #pragma unroll
            for (int g=0; g<4; g++){
                float4 h0 = *(const float4*)&hsh[64 + g*16 +  0];
                float4 h1 = *(const float4*)&hsh[64 + g*16 +  4];
                float4 h2 = *(const float4*)&hsh[64 + g*16 +  8];
                float4 h3 = *(const float4*)&hsh[64 + g*16 + 12];
                float4 wA0 = sb[(g*4+0)*256], wA1 = sb[(g*4+1)*256],
                       wA2 = sb[(g*4+2)*256], wA3 = sb[(g*4+3)*256];
                float4 wB0 = sb[(16+g*4+0)*256], wB1 = sb[(16+g*4+1)*256],
                       wB2 = sb[(16+g*4+2)*256], wB3 = sb[(16+g*4+3)*256];
                a  += (DOT4(wA0,h0)+DOT4(wA1,h1)) + (DOT4(wA2,h2)+DOT4(wA3,h3));
                bb += (DOT4(wB0,h0)+DOT4(wB1,h1)) + (DOT4(wB2,h2)+DOT4(wB3,h3));
            }
        }
        pact2[kh][gr]     = a;
        pact2[kh][gr+256] = bb;
        wg_barrier_lds();

        if (t < 128){
            float p0 = gc.x + pact2[0][j]     + pact2[1][j];
            float p1 = gc.y + pact2[0][j+128] + pact2[1][j+128];
            float p2 = gc.z + pact2[0][j+256] + pact2[1][j+256];
            float p3 = gc.w + pact2[0][j+384] + pact2[1][j+384];
            float i_ = fsig(p0), f_ = fsig(p1), g_ = ftanh(p2), o_ = fsig(p3);
            float cn = f_*c + i_*g_;
            float hn = o_*ftanh(cn);
            float y;
            if (pmv) { c = cn; h = hn; y = hn; } else { y = 0.f; }
            hsh[j] = h;
            op[(size_t)l*(BATCH*256)] = y;
        }
        wg_barrier_lds();
        gc = gn1; gn1 = gn2;
    }
}

// ---------------- Emissions: e[m][t] = lout[m] . W_out[t] + b_out[t] ----------------
__global__ __launch_bounds__(256) void emis_kernel(
    const float* __restrict__ xin, const float* __restrict__ Wo,
    const float* __restrict__ bo, float* __restrict__ e)
{
    __shared__ float Wl[NTAG*260];
    const int tid = threadIdx.x;
    for (int i=tid; i<NTAG*256; i+=256) Wl[(i>>8)*260 + (i&255)] = Wo[i];
    __syncthreads();
    const int m0 = blockIdx.x * 32;
    const int tg = tid & 7;
    const int r  = tid >> 3;
    const float* xr = xin + (size_t)(m0 + r) * 256;
    float a0=0.f, a1=0.f;
    #pragma unroll 8
    for (int k=0;k<256;k+=4){
        float4 xv = *(const float4*)(xr + k);
        float4 w0 = *(const float4*)&Wl[tg*260 + k];
        a0 += xv.x*w0.x + xv.y*w0.y + xv.z*w0.z + xv.w*w0.w;
        if (tg == 0) {
            float4 w8 = *(const float4*)&Wl[8*260 + k];
            a1 += xv.x*w8.x + xv.y*w8.y + xv.z*w8.z + xv.w*w8.w;
        }
    }
    e[(size_t)(m0+r)*NTAG + tg] = a0 + bo[tg];
    if (tg == 0) e[(size_t)(m0+r)*NTAG + 8] = a1 + bo[8];
}

// ---------------- CRF scan: barrier-free wave-local ----------------
__global__ __launch_bounds__(64) void crf_scan(
    const float* __restrict__ e, const int* __restrict__ pm,
    const int* __restrict__ tags,
    const float* __restrict__ stt, const float* __restrict__ ent,
    const float* __restrict__ trans,
    float* __restrict__ logZ, float* __restrict__ num,
    unsigned char* __restrict__ hist, int* __restrict__ bestl)
{
    const int blk  = blockIdx.x;
    const int lane = threadIdx.x;

    if (blk < 10) {
        const int bw = lane / 9;
        const int tp = lane % 9;
        const int b  = blk * 7 + bw;
        const bool act = (bw < 7) && (b < BATCH);
        const int gbase = bw * 9;

        float trc[NTAG];
        #pragma unroll
        for (int t=0;t<NTAG;t++) trc[t] = trans[t*NTAG+tp];
        const float ent_tp = ent[tp];

        int part = 0;
        if (act) for (int l=tp; l<LSEQ; l+=NTAG) part += pm[b*LSEQ + l];
        int len = 0;
        #pragma unroll
        for (int t=0;t<NTAG;t++) len += __shfl(part, gbase + t, 64);

        float ev0 = act ? e[(size_t)b*NTAG + tp] : 0.f;
        float sn = stt[tp] + ev0;
        float sv = sn;

        float evb[8];
        #pragma unroll
        for (int q=0;q<8;q++)
            evb[q] = act ? e[((size_t)(1+q)*BATCH + b)*NTAG + tp] : 0.f;

        unsigned char* hb = hist + (size_t)b*16 + tp;

        for (int l0=1; l0<LSEQ; l0+=8){
            #pragma unroll
            for (int q=0;q<8;q++){
                const int l = l0 + q;
                if (l < LSEQ) {
                    float ev = evb[q];
                    const int lp = l + 8;
                    evb[q] = (act && lp < LSEQ) ? e[((size_t)lp*BATCH + b)*NTAG + tp] : 0.f;

                    float an[NTAG], av[NTAG];
                    #pragma unroll
                    for (int t=0;t<NTAG;t++){
                        an[t] = __shfl(sn, gbase + t, 64) + trc[t];
                        av[t] = __shfl(sv, gbase + t, 64) + trc[t];
                    }
                    float mx = an[0];
                    #pragma unroll
                    for (int t=1;t<NTAG;t++) mx = fmaxf(mx, an[t]);
                    float ss = 0.f;
                    #pragma unroll
                    for (int t=0;t<NTAG;t++) ss += __expf(an[t]-mx);
                    float nxt = mx + __logf(ss) + ev;
                    sn = (l < len) ? nxt : sn;
                    float bv = av[0]; int bi = 0;
                    #pragma unroll
                    for (int t=1;t<NTAG;t++){ if (av[t] > bv){ bv = av[t]; bi = t; } }
                    if (act) hb[(size_t)(l-1)*1024] = (unsigned char)bi;
                    sv = bv + ev;
                }
            }
        }

        float fz = sn + ent_tp;
        float fv = sv + ent_tp;
        float gz[NTAG], gv[NTAG];
        #pragma unroll
        for (int t=0;t<NTAG;t++){
            gz[t] = __shfl(fz, gbase + t, 64);
            gv[t] = __shfl(fv, gbase + t, 64);
        }
        if (act && tp == 0) {
            float mx = gz[0];
            #pragma unroll
            for (int t=1;t<NTAG;t++) mx = fmaxf(mx, gz[t]);
            float ss = 0.f;
            #pragma unroll
            for (int t=0;t<NTAG;t++) ss += __expf(gz[t]-mx);
            logZ[b] = mx + __logf(ss);
            float bv = gv[0]; int bi = 0;
            #pragma unroll
            for (int t=1;t<NTAG;t++){ if (gv[t] > bv){ bv = gv[t]; bi = t; } }
            bestl[b] = bi;
        }
    } else {
        __shared__ float trl[NTAG*NTAG];
        __shared__ float stl[NTAG], enl[NTAG];
        for (int i=lane; i<NTAG*NTAG; i+=64) trl[i] = trans[i];
        if (lane < NTAG) { stl[lane] = stt[lane]; enl[lane] = ent[lane]; }
        __syncthreads();
        const int b = lane;
        int len = 0;
        for (int l=0; l<LSEQ; l+=4){
            int4 p = *(const int4*)&pm[b*LSEQ + l];
            len += p.x + p.y + p.z + p.w;
        }
        int tprev = tags[b*LSEQ];
        float acc = stl[tprev] + e[(size_t)b*NTAG + tprev];
        #pragma unroll 4
        for (int l=1; l<len; l++){
            int tl = tags[b*LSEQ + l];
            acc += trl[tprev*NTAG + tl] + e[((size_t)l*BATCH + b)*NTAG + tl];
            tprev = tl;
        }
        acc += enl[tprev];
        num[b] = acc;
    }
}

// ---------------- Backtrace + loss ----------------
__global__ __launch_bounds__(64) void backtrace_kernel(
    const unsigned char* __restrict__ hist, const int* __restrict__ bestl,
    const int* __restrict__ pm, const float* __restrict__ num,
    const float* __restrict__ logZ, float* __restrict__ out)
{
    const int b = threadIdx.x;
    float d = num[b] - logZ[b];
    #pragma unroll
    for (int off=32; off; off>>=1) d += __shfl_down(d, off);
    if (b == 0) out[0] = -d * (1.0f/64.0f);
    int tag = bestl[b];
    out[1 + b*LSEQ + (LSEQ-1)] = (float)(tag * pm[b*LSEQ + (LSEQ-1)]);
    #pragma unroll 8
    for (int l = LSEQ-2; l >= 0; l--) {
        uint4 row = *(const uint4*)(hist + (size_t)l*1024 + b*16);
        unsigned int wlo  = (tag & 4) ? row.y : row.x;
        unsigned int wsel = (tag & 8) ? row.z : wlo;
        tag = (int)((wsel >> ((tag & 3) * 8)) & 255u);
        out[1 + b*LSEQ + l] = (float)(tag * pm[b*LSEQ + l]);
    }
}

extern "C" void kernel_launch(void* const* d_in, const int* in_sizes, int n_in,
                              void* d_out, int out_size, void* d_ws, size_t ws_size,
                              hipStream_t stream)
{
    (void)in_sizes; (void)n_in; (void)out_size; (void)ws_size;
    const int*   sent  = (const int*)  d_in[0];
    const int*   tags  = (const int*)  d_in[1];
    const int*   pm    = (const int*)  d_in[2];
    const float* emb   = (const float*)d_in[4];
    const float* wihf  = (const float*)d_in[5];
    const float* whhf  = (const float*)d_in[6];
    const float* bf    = (const float*)d_in[7];
    const float* wihb  = (const float*)d_in[8];
    const float* whhb  = (const float*)d_in[9];
    const float* bb    = (const float*)d_in[10];
    const float* Wo    = (const float*)d_in[11];
    const float* bo    = (const float*)d_in[12];
    const float* stt   = (const float*)d_in[13];
    const float* ent   = (const float*)d_in[14];
    const float* trans = (const float*)d_in[15];

    char* ws = (char*)d_ws;
    float* gx            = (float*)(ws);                       // 134217728 B
    float* lout          = (float*)(ws + 134217728);           //  33554432 B
    float* emis          = (float*)(ws + 167772160);           //   1179648 B
    unsigned char* hist  = (unsigned char*)(ws + 168951808);   //    523264 B
    float* numb          = (float*)(ws + 169475072);
    float* logZ          = (float*)(ws + 169475328);
    int*   bestl         = (int*)  (ws + 169475584);
    // sbuf (256KB) ALIASES the hist region: lstm_rec (reads sbuf) completes before
    // crf_scan (writes hist) — stream-serialized, no overlap in time.
    float4* sbuf         = (float4*)(ws + 168951808);

    pack_whh<<<dim3(2,32), 256, 0, stream>>>(whhf, whhb, sbuf);
    dim3 g1(MTOT/GBM, (2*G4)/GBN);   // 256 x 8
    gx_gemm<<<g1, 256, 0, stream>>>(sent, emb, wihf, wihb, bf, bb, gx);
    lstm_rec<<<128, 512, 0, stream>>>(gx, whhf, whhb, pm, sbuf, lout);
    emis_kernel<<<MTOT/32, 256, 0, stream>>>(lout, Wo, bo, emis);
    crf_scan<<<11, 64, 0, stream>>>(emis, pm, tags, stt, ent, trans, logZ, numb, hist, bestl);
    backtrace_kernel<<<1, 64, 0, stream>>>(hist, bestl, pm, numb, logZ, (float*)d_out);
}

// Round 10
// 894.424 us; speedup vs baseline: 1.4823x; 1.4823x over previous
//
#include <hip/hip_runtime.h>
#include <math.h>

#define LSEQ 512
#define BATCH 64
#define EDIM 256
#define HD 128            // H2
#define G4 512            // 4*H2
#define NTAG 9
#define MTOT (LSEQ*BATCH) // 32768

typedef _Float16 f16x8 __attribute__((ext_vector_type(8)));
typedef float    f32x4 __attribute__((ext_vector_type(4)));

__device__ __forceinline__ float fsig(float x){
    return __builtin_amdgcn_rcpf(1.0f + __expf(-x));
}
__device__ __forceinline__ float ftanh(float x){
    return 1.0f - 2.0f*__builtin_amdgcn_rcpf(1.0f + __expf(2.0f*x));
}
// LDS-only barrier: does NOT drain vmcnt, so global prefetches stay in flight.
__device__ __forceinline__ void wg_barrier_lds(){
    asm volatile("s_waitcnt lgkmcnt(0)" ::: "memory");
    __builtin_amdgcn_s_barrier();
    asm volatile("" ::: "memory");
}

// ---------------- GEMM (MFMA, f16 3-term split): gx[dir][l*64+b][j] = emb[sent[b][l]] . w_ih[j] + bias
#define GBM 128
#define GBN 128
__global__ __launch_bounds__(256) void gx_gemm(
    const int* __restrict__ sent, const float* __restrict__ emb,
    const float* __restrict__ wf, const float* __restrict__ wb,
    const float* __restrict__ bf, const float* __restrict__ bb,
    float* __restrict__ gx)
{
    __shared__ f16x8 Ah[512], Am[512], Bh[512], Bm[512];
    __shared__ int sidx[GBM];
    const int tid = threadIdx.x;
    const int bm0 = blockIdx.x * GBM;
    const int bn0 = blockIdx.y * GBN;
    if (tid < GBM){
        int m = bm0 + tid;
        sidx[tid] = sent[(m & 63)*LSEQ + (m >> 6)];
    }
    __syncthreads();

    const float* srcA[2];
    const float* srcB[2];
    #pragma unroll
    for (int p=0;p<2;p++){
        const int d   = tid + 256*p;
        const int row = (d>>6)*16 + (d&15);
        const int kq  = (d>>4)&3;
        srcA[p] = emb + (size_t)sidx[row]*EDIM + kq*8;
        const int col = bn0 + row;
        srcB[p] = ((col < G4) ? (wf + (size_t)col*EDIM)
                              : (wb + (size_t)(col-G4)*EDIM)) + kq*8;
    }

    const int lane = tid & 63;
    const int wid  = tid >> 6;
    const int wm   = wid >> 1;
    const int wn   = wid & 1;

    f32x4 acc[4][4];
    #pragma unroll
    for (int i=0;i<4;i++)
        #pragma unroll
        for (int jj=0;jj<4;jj++)
            #pragma unroll
            for (int e=0;e<4;e++) acc[i][jj][e]=0.f;

    float4 ra[2][2], rb[2][2];
    #define LOADC(K0)  { _Pragma("unroll") for (int p=0;p<2;p++){ \
        ra[p][0] = *(const float4*)(srcA[p] + (K0));  ra[p][1] = *(const float4*)(srcA[p] + (K0) + 4); \
        rb[p][0] = *(const float4*)(srcB[p] + (K0));  rb[p][1] = *(const float4*)(srcB[p] + (K0) + 4); } }

    LOADC(0);
    for (int c=0;c<8;c++){
        wg_barrier_lds();
        #pragma unroll
        for (int p=0;p<2;p++){
            float va[8] = {ra[p][0].x, ra[p][0].y, ra[p][0].z, ra[p][0].w,
                           ra[p][1].x, ra[p][1].y, ra[p][1].z, ra[p][1].w};
            float vb[8] = {rb[p][0].x, rb[p][0].y, rb[p][0].z, rb[p][0].w,
                           rb[p][1].x, rb[p][1].y, rb[p][1].z, rb[p][1].w};
            f16x8 ahh, amm, bhh, bmm;
            #pragma unroll
            for (int i=0;i<8;i++){
                _Float16 hv = (_Float16)va[i];
                ahh[i] = hv; amm[i] = (_Float16)(va[i] - (float)hv);
                _Float16 hw = (_Float16)vb[i];
                bhh[i] = hw; bmm[i] = (_Float16)(vb[i] - (float)hw);
            }
            Ah[tid + 256*p] = ahh;  Am[tid + 256*p] = amm;
            Bh[tid + 256*p] = bhh;  Bm[tid + 256*p] = bmm;
        }
        if (c < 7) LOADC(32*(c+1));
        wg_barrier_lds();

        f16x8 ah[4], am[4];
        #pragma unroll
        for (int mt=0;mt<4;mt++){
            ah[mt] = Ah[(wm*4+mt)*64 + lane];
            am[mt] = Am[(wm*4+mt)*64 + lane];
        }
        #pragma unroll
        for (int nt=0;nt<4;nt++){
            f16x8 bh = Bh[(wn*4+nt)*64 + lane];
            f16x8 bm = Bm[(wn*4+nt)*64 + lane];
            #pragma unroll
            for (int mt=0;mt<4;mt++){
                acc[mt][nt] = __builtin_amdgcn_mfma_f32_16x16x32_f16(ah[mt], bh, acc[mt][nt], 0,0,0);
                acc[mt][nt] = __builtin_amdgcn_mfma_f32_16x16x32_f16(am[mt], bh, acc[mt][nt], 0,0,0);
                acc[mt][nt] = __builtin_amdgcn_mfma_f32_16x16x32_f16(ah[mt], bm, acc[mt][nt], 0,0,0);
            }
        }
    }
    #undef LOADC

    #pragma unroll
    for (int mt=0;mt<4;mt++){
        #pragma unroll
        for (int nt=0;nt<4;nt++){
            const int n   = bn0 + wn*64 + nt*16 + (lane & 15);
            const int dir = n >> 9;
            const int j   = n & 511;
            const float bias = (n < G4) ? bf[n] : bb[n - G4];
            const int mrow = bm0 + wm*64 + mt*16 + ((lane >> 4) << 2);
            float* o = gx + (size_t)dir*((size_t)MTOT*G4) + (size_t)mrow*G4 + j;
            o[0*G4] = acc[mt][nt][0] + bias;
            o[1*G4] = acc[mt][nt][1] + bias;
            o[2*G4] = acc[mt][nt][2] + bias;
            o[3*G4] = acc[mt][nt][3] + bias;
        }
    }
}

// ---------------- Pack W_hh stream-half into coalesced layout.
// Thread t=(kq=t>>7, gr=t&127) owns rows {gr,+128,+256,+384} x k in [kq*32+16, kq*32+32).
// sbuf[dir][i][t]: i = rr*4+m -> row = gr+128*rr, k = kq*32+16+4m. Per-step reads are
// lane-contiguous: 64 lanes x 16B = 1KB per instruction.
__global__ __launch_bounds__(512) void pack_whh(
    const float* __restrict__ whf, const float* __restrict__ whb, float4* __restrict__ sbuf)
{
    const int dir = blockIdx.x;          // 0..1
    const int i   = blockIdx.y;          // 0..15
    const int t   = threadIdx.x;         // 0..511
    const float* W = dir ? whb : whf;
    const int gr  = t & 127, kq = t >> 7;
    const int row = gr + 128*(i >> 2);
    const int k   = kq*32 + 16 + 4*(i & 3);
    sbuf[((size_t)dir*16 + i)*512 + t] = *(const float4*)&W[(size_t)row*HD + k];
}

// ---------------- LSTM recurrence v7: symmetric dual-pipe, conflict-free.
// 128 WGs = (dir,b), 512 threads. Thread (kq,gr) -> rows {gr,+128,+256,+384},
// k-quarter [kq*32,+32): first 16 k from padded LDS cache (stride 17 float4 ->
// bank quad (row+c)%8, 4 lanes/quad/half-wave = ZERO conflicts), last 16 k
// streamed from sbuf (all 8 waves stream -> full TLP). 8 uniform h-reads/thread.
// Per-step: LDS 128KB (1024cyc) || stream 128KB (~1060cyc) on separate pipes.
#define DOT4(W,H) ((W).x*(H).x + (W).y*(H).y + (W).z*(H).z + (W).w*(H).w)
__global__ __launch_bounds__(512) void lstm_rec(
    const float* __restrict__ gx,
    const float* __restrict__ whf, const float* __restrict__ whb,
    const int* __restrict__ pm,
    const float4* __restrict__ sbuf,
    float* __restrict__ lout)
{
    const int wg  = blockIdx.x;      // 0..127
    const int dir = wg >> 6;
    const int b   = wg & 63;
    const int t   = threadIdx.x;     // 0..511
    const int kq  = t >> 7;          // k-quarter 0..3
    const int gr  = t & 127;         // base row
    const int j   = t & 127;         // unit index for update phase (t<128)

    __shared__ float4 wld4[512*17];  // 136KB padded weight cache (k-halves [kq*32,kq*32+16))
    __shared__ float  pact4[4][512];
    __shared__ float  hsh[HD];
    __shared__ int    pms[LSEQ];

    // one-time fill: thread t fills row t (16 float4: c=kq'*4+m <-> k=kq'*32+4m)
    {
        const float* W = dir ? whb : whf;
        const float* wr = &W[(size_t)t*HD];
        #pragma unroll
        for (int c=0;c<16;c++){
            const int k = (c>>2)*32 + 4*(c&3);
            wld4[t*17 + c] = *(const float4*)&wr[k];
        }
    }
    for (int q=t; q<LSEQ; q+=512) pms[q] = pm[b*LSEQ + q];
    if (t < HD) hsh[t] = 0.f;
    float c = 0.f, h = 0.f;

    const size_t stepel = (size_t)BATCH*G4;
    const float* gxb = gx + (size_t)dir*((size_t)MTOT*G4) + (size_t)b*G4
                          + (dir ? (size_t)(LSEQ-1)*stepel : 0);
    const ptrdiff_t dstep = dir ? -(ptrdiff_t)stepel : (ptrdiff_t)stepel;
    float* op = lout + (size_t)b*256 + dir*HD + j;   // used only when t<128

    // depth-2 gx prefetch queue (lgkm-only barriers keep vmcnt in flight)
    float4 gc = {0,0,0,0}, gn1 = {0,0,0,0};
    if (t < 128){
        gc.x  = gxb[j];          gc.y  = gxb[j+128];
        gc.z  = gxb[j+256];      gc.w  = gxb[j+384];
        const float* p1 = gxb + dstep;
        gn1.x = p1[j];           gn1.y = p1[j+128];
        gn1.z = p1[j+256];       gn1.w = p1[j+384];
    }
    wg_barrier_lds();   // wld4 + hsh + pms visible

    const float4* sb = sbuf + (size_t)dir*16*512 + t;   // stream base (stride 512 float4 per i)

    for (int s=0; s<LSEQ; s++){
        float4 gn2 = {0,0,0,0};
        if (t < 128 && s+2 < LSEQ){
            const float* p = gxb + (ptrdiff_t)(s+2)*dstep;
            gn2.x = p[j]; gn2.y = p[j+128]; gn2.z = p[j+256]; gn2.w = p[j+384];
        }
        const int l = dir ? (LSEQ-1-s) : s;
        const int pmv = pms[l];

        float a0=0.f, a1=0.f, a2=0.f, a3=0.f;   // rows gr, +128, +256, +384
        // LDS-cached half of the k-quarter
        #pragma unroll
        for (int m=0;m<4;m++){
            float4 hv = *(const float4*)&hsh[kq*32 + 4*m];
            a0 += DOT4(wld4[(gr     )*17 + kq*4 + m], hv);
            a1 += DOT4(wld4[(gr+128 )*17 + kq*4 + m], hv);
            a2 += DOT4(wld4[(gr+256 )*17 + kq*4 + m], hv);
            a3 += DOT4(wld4[(gr+384 )*17 + kq*4 + m], hv);
        }
        // streamed half of the k-quarter (coalesced; 8-wave TLP hides L2 latency)
        #pragma unroll
        for (int m=0;m<4;m++){
            float4 hv = *(const float4*)&hsh[kq*32 + 16 + 4*m];
            a0 += DOT4(sb[(m    )*512], hv);
            a1 += DOT4(sb[(4+m  )*512], hv);
            a2 += DOT4(sb[(8+m  )*512], hv);
            a3 += DOT4(sb[(12+m )*512], hv);
        }
        pact4[kq][gr]     = a0;
        pact4[kq][gr+128] = a1;
        pact4[kq][gr+256] = a2;
        pact4[kq][gr+384] = a3;
        wg_barrier_lds();

        if (t < 128){
            float p0 = gc.x + ((pact4[0][j]    +pact4[1][j]    )+(pact4[2][j]    +pact4[3][j]    ));
            float p1 = gc.y + ((pact4[0][j+128]+pact4[1][j+128])+(pact4[2][j+128]+pact4[3][j+128]));
            float p2 = gc.z + ((pact4[0][j+256]+pact4[1][j+256])+(pact4[2][j+256]+pact4[3][j+256]));
            float p3 = gc.w + ((pact4[0][j+384]+pact4[1][j+384])+(pact4[2][j+384]+pact4[3][j+384]));
            float i_ = fsig(p0), f_ = fsig(p1), g_ = ftanh(p2), o_ = fsig(p3);
            float cn = f_*c + i_*g_;
            float hn = o_*ftanh(cn);
            float y;
            if (pmv) { c = cn; h = hn; y = hn; } else { y = 0.f; }
            hsh[j] = h;
            op[(size_t)l*(BATCH*256)] = y;
        }
        wg_barrier_lds();
        gc = gn1; gn1 = gn2;
    }
}

// ---------------- Emissions: e[m][t] = lout[m] . W_out[t] + b_out[t] ----------------
__global__ __launch_bounds__(256) void emis_kernel(
    const float* __restrict__ xin, const float* __restrict__ Wo,
    const float* __restrict__ bo, float* __restrict__ e)
{
    __shared__ float Wl[NTAG*260];
    const int tid = threadIdx.x;
    for (int i=tid; i<NTAG*256; i+=256) Wl[(i>>8)*260 + (i&255)] = Wo[i];
    __syncthreads();
    const int m0 = blockIdx.x * 32;
    const int tg = tid & 7;
    const int r  = tid >> 3;
    const float* xr = xin + (size_t)(m0 + r) * 256;
    float a0=0.f, a1=0.f;
    #pragma unroll 8
    for (int k=0;k<256;k+=4){
        float4 xv = *(const float4*)(xr + k);
        float4 w0 = *(const float4*)&Wl[tg*260 + k];
        a0 += xv.x*w0.x + xv.y*w0.y + xv.z*w0.z + xv.w*w0.w;
        if (tg == 0) {
            float4 w8 = *(const float4*)&Wl[8*260 + k];
            a1 += xv.x*w8.x + xv.y*w8.y + xv.z*w8.z + xv.w*w8.w;
        }
    }
    e[(size_t)(m0+r)*NTAG + tg] = a0 + bo[tg];
    if (tg == 0) e[(size_t)(m0+r)*NTAG + 8] = a1 + bo[8];
}

// ---------------- CRF scan: barrier-free wave-local ----------------
__global__ __launch_bounds__(64) void crf_scan(
    const float* __restrict__ e, const int* __restrict__ pm,
    const int* __restrict__ tags,
    const float* __restrict__ stt, const float* __restrict__ ent,
    const float* __restrict__ trans,
    float* __restrict__ logZ, float* __restrict__ num,
    unsigned char* __restrict__ hist, int* __restrict__ bestl)
{
    const int blk  = blockIdx.x;
    const int lane = threadIdx.x;

    if (blk < 10) {
        const int bw = lane / 9;
        const int tp = lane % 9;
        const int b  = blk * 7 + bw;
        const bool act = (bw < 7) && (b < BATCH);
        const int gbase = bw * 9;

        float trc[NTAG];
        #pragma unroll
        for (int t=0;t<NTAG;t++) trc[t] = trans[t*NTAG+tp];
        const float ent_tp = ent[tp];

        int part = 0;
        if (act) for (int l=tp; l<LSEQ; l+=NTAG) part += pm[b*LSEQ + l];
        int len = 0;
        #pragma unroll
        for (int t=0;t<NTAG;t++) len += __shfl(part, gbase + t, 64);

        float ev0 = act ? e[(size_t)b*NTAG + tp] : 0.f;
        float sn = stt[tp] + ev0;
        float sv = sn;

        float evb[8];
        #pragma unroll
        for (int q=0;q<8;q++)
            evb[q] = act ? e[((size_t)(1+q)*BATCH + b)*NTAG + tp] : 0.f;

        unsigned char* hb = hist + (size_t)b*16 + tp;

        for (int l0=1; l0<LSEQ; l0+=8){
            #pragma unroll
            for (int q=0;q<8;q++){
                const int l = l0 + q;
                if (l < LSEQ) {
                    float ev = evb[q];
                    const int lp = l + 8;
                    evb[q] = (act && lp < LSEQ) ? e[((size_t)lp*BATCH + b)*NTAG + tp] : 0.f;

                    float an[NTAG], av[NTAG];
                    #pragma unroll
                    for (int t=0;t<NTAG;t++){
                        an[t] = __shfl(sn, gbase + t, 64) + trc[t];
                        av[t] = __shfl(sv, gbase + t, 64) + trc[t];
                    }
                    float mx = an[0];
                    #pragma unroll
                    for (int t=1;t<NTAG;t++) mx = fmaxf(mx, an[t]);
                    float ss = 0.f;
                    #pragma unroll
                    for (int t=0;t<NTAG;t++) ss += __expf(an[t]-mx);
                    float nxt = mx + __logf(ss) + ev;
                    sn = (l < len) ? nxt : sn;
                    float bv = av[0]; int bi = 0;
                    #pragma unroll
                    for (int t=1;t<NTAG;t++){ if (av[t] > bv){ bv = av[t]; bi = t; } }
                    if (act) hb[(size_t)(l-1)*1024] = (unsigned char)bi;
                    sv = bv + ev;
                }
            }
        }

        float fz = sn + ent_tp;
        float fv = sv + ent_tp;
        float gz[NTAG], gv[NTAG];
        #pragma unroll
        for (int t=0;t<NTAG;t++){
            gz[t] = __shfl(fz, gbase + t, 64);
            gv[t] = __shfl(fv, gbase + t, 64);
        }
        if (act && tp == 0) {
            float mx = gz[0];
            #pragma unroll
            for (int t=1;t<NTAG;t++) mx = fmaxf(mx, gz[t]);
            float ss = 0.f;
            #pragma unroll
            for (int t=0;t<NTAG;t++) ss += __expf(gz[t]-mx);
            logZ[b] = mx + __logf(ss);
            float bv = gv[0]; int bi = 0;
            #pragma unroll
            for (int t=1;t<NTAG;t++){ if (gv[t] > bv){ bv = gv[t]; bi = t; } }
            bestl[b] = bi;
        }
    } else {
        __shared__ float trl[NTAG*NTAG];
        __shared__ float stl[NTAG], enl[NTAG];
        for (int i=lane; i<NTAG*NTAG; i+=64) trl[i] = trans[i];
        if (lane < NTAG) { stl[lane] = stt[lane]; enl[lane] = ent[lane]; }
        __syncthreads();
        const int b = lane;
        int len = 0;
        for (int l=0; l<LSEQ; l+=4){
            int4 p = *(const int4*)&pm[b*LSEQ + l];
            len += p.x + p.y + p.z + p.w;
        }
        int tprev = tags[b*LSEQ];
        float acc = stl[tprev] + e[(size_t)b*NTAG + tprev];
        #pragma unroll 4
        for (int l=1; l<len; l++){
            int tl = tags[b*LSEQ + l];
            acc += trl[tprev*NTAG + tl] + e[((size_t)l*BATCH + b)*NTAG + tl];
            tprev = tl;
        }
        acc += enl[tprev];
        num[b] = acc;
    }
}

// ---------------- Backtrace + loss ----------------
__global__ __launch_bounds__(64) void backtrace_kernel(
    const unsigned char* __restrict__ hist, const int* __restrict__ bestl,
    const int* __restrict__ pm, const float* __restrict__ num,
    const float* __restrict__ logZ, float* __restrict__ out)
{
    const int b = threadIdx.x;
    float d = num[b] - logZ[b];
    #pragma unroll
    for (int off=32; off; off>>=1) d += __shfl_down(d, off);
    if (b == 0) out[0] = -d * (1.0f/64.0f);
    int tag = bestl[b];
    out[1 + b*LSEQ + (LSEQ-1)] = (float)(tag * pm[b*LSEQ + (LSEQ-1)]);
    #pragma unroll 8
    for (int l = LSEQ-2; l >= 0; l--) {
        uint4 row = *(const uint4*)(hist + (size_t)l*1024 + b*16);
        unsigned int wlo  = (tag & 4) ? row.y : row.x;
        unsigned int wsel = (tag & 8) ? row.z : wlo;
        tag = (int)((wsel >> ((tag & 3) * 8)) & 255u);
        out[1 + b*LSEQ + l] = (float)(tag * pm[b*LSEQ + l]);
    }
}

extern "C" void kernel_launch(void* const* d_in, const int* in_sizes, int n_in,
                              void* d_out, int out_size, void* d_ws, size_t ws_size,
                              hipStream_t stream)
{
    (void)in_sizes; (void)n_in; (void)out_size; (void)ws_size;
    const int*   sent  = (const int*)  d_in[0];
    const int*   tags  = (const int*)  d_in[1];
    const int*   pm    = (const int*)  d_in[2];
    const float* emb   = (const float*)d_in[4];
    const float* wihf  = (const float*)d_in[5];
    const float* whhf  = (const float*)d_in[6];
    const float* bf    = (const float*)d_in[7];
    const float* wihb  = (const float*)d_in[8];
    const float* whhb  = (const float*)d_in[9];
    const float* bb    = (const float*)d_in[10];
    const float* Wo    = (const float*)d_in[11];
    const float* bo    = (const float*)d_in[12];
    const float* stt   = (const float*)d_in[13];
    const float* ent   = (const float*)d_in[14];
    const float* trans = (const float*)d_in[15];

    char* ws = (char*)d_ws;
    float* gx            = (float*)(ws);                       // 134217728 B
    float* lout          = (float*)(ws + 134217728);           //  33554432 B
    float* emis          = (float*)(ws + 167772160);           //   1179648 B
    unsigned char* hist  = (unsigned char*)(ws + 168951808);   //    523264 B
    float* numb          = (float*)(ws + 169475072);
    float* logZ          = (float*)(ws + 169475328);
    int*   bestl         = (int*)  (ws + 169475584);
    // sbuf (256KB) ALIASES the hist region: lstm_rec (reads sbuf) completes before
    // crf_scan (writes hist) — stream-serialized, no overlap in time.
    float4* sbuf         = (float4*)(ws + 168951808);

    pack_whh<<<dim3(2,16), 512, 0, stream>>>(whhf, whhb, sbuf);
    dim3 g1(MTOT/GBM, (2*G4)/GBN);   // 256 x 8
    gx_gemm<<<g1, 256, 0, stream>>>(sent, emb, wihf, wihb, bf, bb, gx);
    lstm_rec<<<128, 512, 0, stream>>>(gx, whhf, whhb, pm, sbuf, lout);
    emis_kernel<<<MTOT/32, 256, 0, stream>>>(lout, Wo, bo, emis);
    crf_scan<<<11, 64, 0, stream>>>(emis, pm, tags, stt, ent, trans, logZ, numb, hist, bestl);
    backtrace_kernel<<<1, 64, 0, stream>>>(hist, bestl, pm, numb, logZ, (float*)d_out);
}

// Round 11
// 855.398 us; speedup vs baseline: 1.5499x; 1.0456x over previous
//
#include <hip/hip_runtime.h>
#include <math.h>

#define LSEQ 512
#define BATCH 64
#define EDIM 256
#define HD 128            // H2
#define G4 512            // 4*H2
#define NTAG 9
#define MTOT (LSEQ*BATCH) // 32768

typedef _Float16 f16x8 __attribute__((ext_vector_type(8)));
typedef float    f32x4 __attribute__((ext_vector_type(4)));

__device__ __forceinline__ float fsig(float x){
    return __builtin_amdgcn_rcpf(1.0f + __expf(-x));
}
__device__ __forceinline__ float ftanh(float x){
    return 1.0f - 2.0f*__builtin_amdgcn_rcpf(1.0f + __expf(2.0f*x));
}
// LDS-only barrier: does NOT drain vmcnt, so global prefetches stay in flight.
__device__ __forceinline__ void wg_barrier_lds(){
    asm volatile("s_waitcnt lgkmcnt(0)" ::: "memory");
    __builtin_amdgcn_s_barrier();
    asm volatile("" ::: "memory");
}

// ---------------- GEMM (MFMA, f16 3-term split): gx[dir][l*64+b][j] = emb[sent[b][l]] . w_ih[j] + bias
#define GBM 128
#define GBN 128
__global__ __launch_bounds__(256) void gx_gemm(
    const int* __restrict__ sent, const float* __restrict__ emb,
    const float* __restrict__ wf, const float* __restrict__ wb,
    const float* __restrict__ bf, const float* __restrict__ bb,
    float* __restrict__ gx)
{
    __shared__ f16x8 Ah[512], Am[512], Bh[512], Bm[512];
    __shared__ int sidx[GBM];
    const int tid = threadIdx.x;
    const int bm0 = blockIdx.x * GBM;
    const int bn0 = blockIdx.y * GBN;
    if (tid < GBM){
        int m = bm0 + tid;
        sidx[tid] = sent[(m & 63)*LSEQ + (m >> 6)];
    }
    __syncthreads();

    const float* srcA[2];
    const float* srcB[2];
    #pragma unroll
    for (int p=0;p<2;p++){
        const int d   = tid + 256*p;
        const int row = (d>>6)*16 + (d&15);
        const int kq  = (d>>4)&3;
        srcA[p] = emb + (size_t)sidx[row]*EDIM + kq*8;
        const int col = bn0 + row;
        srcB[p] = ((col < G4) ? (wf + (size_t)col*EDIM)
                              : (wb + (size_t)(col-G4)*EDIM)) + kq*8;
    }

    const int lane = tid & 63;
    const int wid  = tid >> 6;
    const int wm   = wid >> 1;
    const int wn   = wid & 1;

    f32x4 acc[4][4];
    #pragma unroll
    for (int i=0;i<4;i++)
        #pragma unroll
        for (int jj=0;jj<4;jj++)
            #pragma unroll
            for (int e=0;e<4;e++) acc[i][jj][e]=0.f;

    float4 ra[2][2], rb[2][2];
    #define LOADC(K0)  { _Pragma("unroll") for (int p=0;p<2;p++){ \
        ra[p][0] = *(const float4*)(srcA[p] + (K0));  ra[p][1] = *(const float4*)(srcA[p] + (K0) + 4); \
        rb[p][0] = *(const float4*)(srcB[p] + (K0));  rb[p][1] = *(const float4*)(srcB[p] + (K0) + 4); } }

    LOADC(0);
    for (int c=0;c<8;c++){
        wg_barrier_lds();
        #pragma unroll
        for (int p=0;p<2;p++){
            float va[8] = {ra[p][0].x, ra[p][0].y, ra[p][0].z, ra[p][0].w,
                           ra[p][1].x, ra[p][1].y, ra[p][1].z, ra[p][1].w};
            float vb[8] = {rb[p][0].x, rb[p][0].y, rb[p][0].z, rb[p][0].w,
                           rb[p][1].x, rb[p][1].y, rb[p][1].z, rb[p][1].w};
            f16x8 ahh, amm, bhh, bmm;
            #pragma unroll
            for (int i=0;i<8;i++){
                _Float16 hv = (_Float16)va[i];
                ahh[i] = hv; amm[i] = (_Float16)(va[i] - (float)hv);
                _Float16 hw = (_Float16)vb[i];
                bhh[i] = hw; bmm[i] = (_Float16)(vb[i] - (float)hw);
            }
            Ah[tid + 256*p] = ahh;  Am[tid + 256*p] = amm;
            Bh[tid + 256*p] = bhh;  Bm[tid + 256*p] = bmm;
        }
        if (c < 7) LOADC(32*(c+1));
        wg_barrier_lds();

        f16x8 ah[4], am[4];
        #pragma unroll
        for (int mt=0;mt<4;mt++){
            ah[mt] = Ah[(wm*4+mt)*64 + lane];
            am[mt] = Am[(wm*4+mt)*64 + lane];
        }
        #pragma unroll
        for (int nt=0;nt<4;nt++){
            f16x8 bh = Bh[(wn*4+nt)*64 + lane];
            f16x8 bm = Bm[(wn*4+nt)*64 + lane];
            #pragma unroll
            for (int mt=0;mt<4;mt++){
                acc[mt][nt] = __builtin_amdgcn_mfma_f32_16x16x32_f16(ah[mt], bh, acc[mt][nt], 0,0,0);
                acc[mt][nt] = __builtin_amdgcn_mfma_f32_16x16x32_f16(am[mt], bh, acc[mt][nt], 0,0,0);
                acc[mt][nt] = __builtin_amdgcn_mfma_f32_16x16x32_f16(ah[mt], bm, acc[mt][nt], 0,0,0);
            }
        }
    }
    #undef LOADC

    #pragma unroll
    for (int mt=0;mt<4;mt++){
        #pragma unroll
        for (int nt=0;nt<4;nt++){
            const int n   = bn0 + wn*64 + nt*16 + (lane & 15);
            const int dir = n >> 9;
            const int j   = n & 511;
            const float bias = (n < G4) ? bf[n] : bb[n - G4];
            const int mrow = bm0 + wm*64 + mt*16 + ((lane >> 4) << 2);
            float* o = gx + (size_t)dir*((size_t)MTOT*G4) + (size_t)mrow*G4 + j;
            o[0*G4] = acc[mt][nt][0] + bias;
            o[1*G4] = acc[mt][nt][1] + bias;
            o[2*G4] = acc[mt][nt][2] + bias;
            o[3*G4] = acc[mt][nt][3] + bias;
        }
    }
}

// ---------------- Pack W_hh stream-portion into coalesced layout.
// Thread t=(kq=t>>7, gr=t&127) owns rows {gr,+128,+256,+384} x k in [kq*32+8, kq*32+32).
// sbuf[dir][i][t]: i = rr*6+m -> row = gr+128*rr, k = kq*32+8+4m. Per-step reads are
// lane-contiguous: 64 lanes x 16B = 1KB per instruction.
__global__ __launch_bounds__(512) void pack_whh(
    const float* __restrict__ whf, const float* __restrict__ whb, float4* __restrict__ sbuf)
{
    const int dir = blockIdx.x;          // 0..1
    const int i   = blockIdx.y;          // 0..23
    const int t   = threadIdx.x;         // 0..511
    const float* W = dir ? whb : whf;
    const int gr  = t & 127, kq = t >> 7;
    const int row = gr + 128*(i / 6);
    const int k   = kq*32 + 8 + 4*(i % 6);
    sbuf[((size_t)dir*24 + i)*512 + t] = *(const float4*)&W[(size_t)row*HD + k];
}

// ---------------- LSTM recurrence v8: rebalanced dual-pipe (validated model, R10 post-mortem).
// Per step per WG: stream 192KB (24/32 of W, port ~1612cyc) || LDS 64KB cache (8/32 of W,
// 64 instr) + h/pact traffic. x=0.75 sits at the model's optimum: max(1612, ~1450-1850).
// stride-9 float4 pad -> bank quad (row+c)%8, the same formula that measured ZERO
// conflicts at stride 17 in R10.
#define DOT4(W,H) ((W).x*(H).x + (W).y*(H).y + (W).z*(H).z + (W).w*(H).w)
__global__ __launch_bounds__(512) void lstm_rec(
    const float* __restrict__ gx,
    const float* __restrict__ whf, const float* __restrict__ whb,
    const int* __restrict__ pm,
    const float4* __restrict__ sbuf,
    float* __restrict__ lout)
{
    const int wg  = blockIdx.x;      // 0..127
    const int dir = wg >> 6;
    const int b   = wg & 63;
    const int t   = threadIdx.x;     // 0..511
    const int kq  = t >> 7;          // k-quarter 0..3
    const int gr  = t & 127;         // base row
    const int j   = t & 127;         // unit index for update phase (t<128)

    __shared__ float4 wld4[512*9];   // 72KB padded weight cache (k in [kq*32, kq*32+8) per row)
    __shared__ float  pact4[4][512];
    __shared__ float  hsh[HD];
    __shared__ int    pms[LSEQ];

    // one-time fill: thread t fills row t (8 float4: c=kq'*2+m <-> k=kq'*32+4m, m in {0,1})
    {
        const float* W = dir ? whb : whf;
        const float* wr = &W[(size_t)t*HD];
        #pragma unroll
        for (int c=0;c<8;c++){
            const int k = (c>>1)*32 + 4*(c&1);
            wld4[t*9 + c] = *(const float4*)&wr[k];
        }
    }
    for (int q=t; q<LSEQ; q+=512) pms[q] = pm[b*LSEQ + q];
    if (t < HD) hsh[t] = 0.f;
    float c = 0.f, h = 0.f;

    const size_t stepel = (size_t)BATCH*G4;
    const float* gxb = gx + (size_t)dir*((size_t)MTOT*G4) + (size_t)b*G4
                          + (dir ? (size_t)(LSEQ-1)*stepel : 0);
    const ptrdiff_t dstep = dir ? -(ptrdiff_t)stepel : (ptrdiff_t)stepel;
    float* op = lout + (size_t)b*256 + dir*HD + j;   // used only when t<128

    // depth-2 gx prefetch queue (lgkm-only barriers keep vmcnt in flight)
    float4 gc = {0,0,0,0}, gn1 = {0,0,0,0};
    if (t < 128){
        gc.x  = gxb[j];          gc.y  = gxb[j+128];
        gc.z  = gxb[j+256];      gc.w  = gxb[j+384];
        const float* p1 = gxb + dstep;
        gn1.x = p1[j];           gn1.y = p1[j+128];
        gn1.z = p1[j+256];       gn1.w = p1[j+384];
    }
    wg_barrier_lds();   // wld4 + hsh + pms visible

    const float4* sb = sbuf + (size_t)dir*24*512 + t;   // stream base (stride 512 float4 per i)

    for (int s=0; s<LSEQ; s++){
        float4 gn2 = {0,0,0,0};
        if (t < 128 && s+2 < LSEQ){
            const float* p = gxb + (ptrdiff_t)(s+2)*dstep;
            gn2.x = p[j]; gn2.y = p[j+128]; gn2.z = p[j+256]; gn2.w = p[j+384];
        }
        const int l = dir ? (LSEQ-1-s) : s;
        const int pmv = pms[l];

        float a0=0.f, a1=0.f, a2=0.f, a3=0.f;   // rows gr, +128, +256, +384
        // LDS-cached: k in [kq*32, kq*32+8)
        #pragma unroll
        for (int m=0;m<2;m++){
            float4 hv = *(const float4*)&hsh[kq*32 + 4*m];
            const int cc = kq*2 + m;
            a0 += DOT4(wld4[(gr     )*9 + cc], hv);
            a1 += DOT4(wld4[(gr+128 )*9 + cc], hv);
            a2 += DOT4(wld4[(gr+256 )*9 + cc], hv);
            a3 += DOT4(wld4[(gr+384 )*9 + cc], hv);
        }
        // streamed: k in [kq*32+8, kq*32+32) (coalesced; 8-wave TLP; hides under LDS work)
        #pragma unroll
        for (int m=0;m<6;m++){
            float4 hv = *(const float4*)&hsh[kq*32 + 8 + 4*m];
            a0 += DOT4(sb[(m     )*512], hv);
            a1 += DOT4(sb[( 6+m  )*512], hv);
            a2 += DOT4(sb[(12+m  )*512], hv);
            a3 += DOT4(sb[(18+m  )*512], hv);
        }
        pact4[kq][gr]     = a0;
        pact4[kq][gr+128] = a1;
        pact4[kq][gr+256] = a2;
        pact4[kq][gr+384] = a3;
        wg_barrier_lds();

        if (t < 128){
            float p0 = gc.x + ((pact4[0][j]    +pact4[1][j]    )+(pact4[2][j]    +pact4[3][j]    ));
            float p1 = gc.y + ((pact4[0][j+128]+pact4[1][j+128])+(pact4[2][j+128]+pact4[3][j+128]));
            float p2 = gc.z + ((pact4[0][j+256]+pact4[1][j+256])+(pact4[2][j+256]+pact4[3][j+256]));
            float p3 = gc.w + ((pact4[0][j+384]+pact4[1][j+384])+(pact4[2][j+384]+pact4[3][j+384]));
            float i_ = fsig(p0), f_ = fsig(p1), g_ = ftanh(p2), o_ = fsig(p3);
            float cn = f_*c + i_*g_;
            float hn = o_*ftanh(cn);
            float y;
            if (pmv) { c = cn; h = hn; y = hn; } else { y = 0.f; }
            hsh[j] = h;
            op[(size_t)l*(BATCH*256)] = y;
        }
        wg_barrier_lds();
        gc = gn1; gn1 = gn2;
    }
}

// ---------------- Emissions: e[m][t] = lout[m] . W_out[t] + b_out[t] ----------------
__global__ __launch_bounds__(256) void emis_kernel(
    const float* __restrict__ xin, const float* __restrict__ Wo,
    const float* __restrict__ bo, float* __restrict__ e)
{
    __shared__ float Wl[NTAG*260];
    const int tid = threadIdx.x;
    for (int i=tid; i<NTAG*256; i+=256) Wl[(i>>8)*260 + (i&255)] = Wo[i];
    __syncthreads();
    const int m0 = blockIdx.x * 32;
    const int tg = tid & 7;
    const int r  = tid >> 3;
    const float* xr = xin + (size_t)(m0 + r) * 256;
    float a0=0.f, a1=0.f;
    #pragma unroll 8
    for (int k=0;k<256;k+=4){
        float4 xv = *(const float4*)(xr + k);
        float4 w0 = *(const float4*)&Wl[tg*260 + k];
        a0 += xv.x*w0.x + xv.y*w0.y + xv.z*w0.z + xv.w*w0.w;
        if (tg == 0) {
            float4 w8 = *(const float4*)&Wl[8*260 + k];
            a1 += xv.x*w8.x + xv.y*w8.y + xv.z*w8.z + xv.w*w8.w;
        }
    }
    e[(size_t)(m0+r)*NTAG + tg] = a0 + bo[tg];
    if (tg == 0) e[(size_t)(m0+r)*NTAG + 8] = a1 + bo[8];
}

// ---------------- CRF scan: barrier-free wave-local ----------------
__global__ __launch_bounds__(64) void crf_scan(
    const float* __restrict__ e, const int* __restrict__ pm,
    const int* __restrict__ tags,
    const float* __restrict__ stt, const float* __restrict__ ent,
    const float* __restrict__ trans,
    float* __restrict__ logZ, float* __restrict__ num,
    unsigned char* __restrict__ hist, int* __restrict__ bestl)
{
    const int blk  = blockIdx.x;
    const int lane = threadIdx.x;

    if (blk < 10) {
        const int bw = lane / 9;
        const int tp = lane % 9;
        const int b  = blk * 7 + bw;
        const bool act = (bw < 7) && (b < BATCH);
        const int gbase = bw * 9;

        float trc[NTAG];
        #pragma unroll
        for (int t=0;t<NTAG;t++) trc[t] = trans[t*NTAG+tp];
        const float ent_tp = ent[tp];

        int part = 0;
        if (act) for (int l=tp; l<LSEQ; l+=NTAG) part += pm[b*LSEQ + l];
        int len = 0;
        #pragma unroll
        for (int t=0;t<NTAG;t++) len += __shfl(part, gbase + t, 64);

        float ev0 = act ? e[(size_t)b*NTAG + tp] : 0.f;
        float sn = stt[tp] + ev0;
        float sv = sn;

        float evb[8];
        #pragma unroll
        for (int q=0;q<8;q++)
            evb[q] = act ? e[((size_t)(1+q)*BATCH + b)*NTAG + tp] : 0.f;

        unsigned char* hb = hist + (size_t)b*16 + tp;

        for (int l0=1; l0<LSEQ; l0+=8){
            #pragma unroll
            for (int q=0;q<8;q++){
                const int l = l0 + q;
                if (l < LSEQ) {
                    float ev = evb[q];
                    const int lp = l + 8;
                    evb[q] = (act && lp < LSEQ) ? e[((size_t)lp*BATCH + b)*NTAG + tp] : 0.f;

                    float an[NTAG], av[NTAG];
                    #pragma unroll
                    for (int t=0;t<NTAG;t++){
                        an[t] = __shfl(sn, gbase + t, 64) + trc[t];
                        av[t] = __shfl(sv, gbase + t, 64) + trc[t];
                    }
                    float mx = an[0];
                    #pragma unroll
                    for (int t=1;t<NTAG;t++) mx = fmaxf(mx, an[t]);
                    float ss = 0.f;
                    #pragma unroll
                    for (int t=0;t<NTAG;t++) ss += __expf(an[t]-mx);
                    float nxt = mx + __logf(ss) + ev;
                    sn = (l < len) ? nxt : sn;
                    float bv = av[0]; int bi = 0;
                    #pragma unroll
                    for (int t=1;t<NTAG;t++){ if (av[t] > bv){ bv = av[t]; bi = t; } }
                    if (act) hb[(size_t)(l-1)*1024] = (unsigned char)bi;
                    sv = bv + ev;
                }
            }
        }

        float fz = sn + ent_tp;
        float fv = sv + ent_tp;
        float gz[NTAG], gv[NTAG];
        #pragma unroll
        for (int t=0;t<NTAG;t++){
            gz[t] = __shfl(fz, gbase + t, 64);
            gv[t] = __shfl(fv, gbase + t, 64);
        }
        if (act && tp == 0) {
            float mx = gz[0];
            #pragma unroll
            for (int t=1;t<NTAG;t++) mx = fmaxf(mx, gz[t]);
            float ss = 0.f;
            #pragma unroll
            for (int t=0;t<NTAG;t++) ss += __expf(gz[t]-mx);
            logZ[b] = mx + __logf(ss);
            float bv = gv[0]; int bi = 0;
            #pragma unroll
            for (int t=1;t<NTAG;t++){ if (gv[t] > bv){ bv = gv[t]; bi = t; } }
            bestl[b] = bi;
        }
    } else {
        __shared__ float trl[NTAG*NTAG];
        __shared__ float stl[NTAG], enl[NTAG];
        for (int i=lane; i<NTAG*NTAG; i+=64) trl[i] = trans[i];
        if (lane < NTAG) { stl[lane] = stt[lane]; enl[lane] = ent[lane]; }
        __syncthreads();
        const int b = lane;
        int len = 0;
        for (int l=0; l<LSEQ; l+=4){
            int4 p = *(const int4*)&pm[b*LSEQ + l];
            len += p.x + p.y + p.z + p.w;
        }
        int tprev = tags[b*LSEQ];
        float acc = stl[tprev] + e[(size_t)b*NTAG + tprev];
        #pragma unroll 4
        for (int l=1; l<len; l++){
            int tl = tags[b*LSEQ + l];
            acc += trl[tprev*NTAG + tl] + e[((size_t)l*BATCH + b)*NTAG + tl];
            tprev = tl;
        }
        acc += enl[tprev];
        num[b] = acc;
    }
}

// ---------------- Backtrace + loss ----------------
__global__ __launch_bounds__(64) void backtrace_kernel(
    const unsigned char* __restrict__ hist, const int* __restrict__ bestl,
    const int* __restrict__ pm, const float* __restrict__ num,
    const float* __restrict__ logZ, float* __restrict__ out)
{
    const int b = threadIdx.x;
    float d = num[b] - logZ[b];
    #pragma unroll
    for (int off=32; off; off>>=1) d += __shfl_down(d, off);
    if (b == 0) out[0] = -d * (1.0f/64.0f);
    int tag = bestl[b];
    out[1 + b*LSEQ + (LSEQ-1)] = (float)(tag * pm[b*LSEQ + (LSEQ-1)]);
    #pragma unroll 8
    for (int l = LSEQ-2; l >= 0; l--) {
        uint4 row = *(const uint4*)(hist + (size_t)l*1024 + b*16);
        unsigned int wlo  = (tag & 4) ? row.y : row.x;
        unsigned int wsel = (tag & 8) ? row.z : wlo;
        tag = (int)((wsel >> ((tag & 3) * 8)) & 255u);
        out[1 + b*LSEQ + l] = (float)(tag * pm[b*LSEQ + l]);
    }
}

extern "C" void kernel_launch(void* const* d_in, const int* in_sizes, int n_in,
                              void* d_out, int out_size, void* d_ws, size_t ws_size,
                              hipStream_t stream)
{
    (void)in_sizes; (void)n_in; (void)out_size; (void)ws_size;
    const int*   sent  = (const int*)  d_in[0];
    const int*   tags  = (const int*)  d_in[1];
    const int*   pm    = (const int*)  d_in[2];
    const float* emb   = (const float*)d_in[4];
    const float* wihf  = (const float*)d_in[5];
    const float* whhf  = (const float*)d_in[6];
    const float* bf    = (const float*)d_in[7];
    const float* wihb  = (const float*)d_in[8];
    const float* whhb  = (const float*)d_in[9];
    const float* bb    = (const float*)d_in[10];
    const float* Wo    = (const float*)d_in[11];
    const float* bo    = (const float*)d_in[12];
    const float* stt   = (const float*)d_in[13];
    const float* ent   = (const float*)d_in[14];
    const float* trans = (const float*)d_in[15];

    char* ws = (char*)d_ws;
    float* gx            = (float*)(ws);                       // 134217728 B
    float* lout          = (float*)(ws + 134217728);           //  33554432 B
    float* emis          = (float*)(ws + 167772160);           //   1179648 B
    unsigned char* hist  = (unsigned char*)(ws + 168951808);   //    523264 B
    float* numb          = (float*)(ws + 169475072);
    float* logZ          = (float*)(ws + 169475328);
    int*   bestl         = (int*)  (ws + 169475584);
    // sbuf (384KB) ALIASES the hist region: lstm_rec (reads sbuf) completes before
    // crf_scan (writes hist) — stream-serialized, no overlap in time.
    float4* sbuf         = (float4*)(ws + 168951808);

    pack_whh<<<dim3(2,24), 512, 0, stream>>>(whhf, whhb, sbuf);
    dim3 g1(MTOT/GBM, (2*G4)/GBN);   // 256 x 8
    gx_gemm<<<g1, 256, 0, stream>>>(sent, emb, wihf, wihb, bf, bb, gx);
    lstm_rec<<<128, 512, 0, stream>>>(gx, whhf, whhb, pm, sbuf, lout);
    emis_kernel<<<MTOT/32, 256, 0, stream>>>(lout, Wo, bo, emis);
    crf_scan<<<11, 64, 0, stream>>>(emis, pm, tags, stt, ent, trans, logZ, numb, hist, bestl);
    backtrace_kernel<<<1, 64, 0, stream>>>(hist, bestl, pm, numb, logZ, (float*)d_out);
}